// Round 7
// baseline (258.505 us; speedup 1.0000x reference)
//
#include <hip/hip_runtime.h>
#include <math.h>

// ---------------------------------------------------------------------------
// R22. R20/R21 proved register-staged weight staging is infeasible: at 16
// waves/CU the unified VGPR+AGPR budget is 128/wave (512/SIMD / 4 waves);
// P9's 64 accs + working set leave no room for 56 staged regs -> allocator
// spills them to scratch (57MB WRITE_SIZE) regardless of launch bounds.
// Fix: stage weights with __builtin_amdgcn_global_load_lds (global->LDS DMA,
// ZERO VGPR footprint, async on vmcnt). Staging layout is exactly the
// wave-uniform-base + lane*16B linear pattern the instruction requires.
//   - cx_w1 + as_w2 issued at kernel top (covered by P0/A/B phases)
//   - cx_w2 issued right after L1's closing barrier (+1 barrier, ~1us drain)
//   - W_t1|W_P issued right after L2's closing barrier (+1 barrier)
//   - as_w2 lives in its own abuf (8KB), never overwritten
// L1/L2/P7/P9 read weights from LDS via uniform-address ds_read_b128
// (broadcast, conflict-free, in-order lgkmcnt). Small phases keep s_load.
// LDS: bufA 38KB + bufB 32KB + wbuf 76.8KB + abuf 8KB = 156.7KB (1 block/CU).
// ws layout (floats): [0:1920) Qa | [1920:1950) strength | [1950:1980) hasv |
//   [2048:10240) W_t1 | [10240:10304) b_t1 | [10304:18496) W_P | [18496:18560) b_P
// ---------------------------------------------------------------------------

__device__ __forceinline__ float4 ld4(const float* p) {
  return *(const float4*)p;
}

// global->LDS DMA, 16B per lane. lds dest is wave-uniform base + lane*16.
__device__ __forceinline__ void glds16(const float* g, float* l) {
  __builtin_amdgcn_global_load_lds(
      (const __attribute__((address_space(1))) void*)g,
      (__attribute__((address_space(3))) void*)l, 16, 0, 0);
}

__device__ __forceinline__ void encode_card32(int c,
                                              const float* __restrict__ val_emb,
                                              const float* __restrict__ suit_emb,
                                              const float* __restrict__ type_emb,
                                              float* e) {
  bool inv = (c == 0) || (c == 53);
  int v = inv ? 0 : ((c - 1) % 13 + 1);
  int s = inv ? 0 : ((c - 1) / 13 + 1);
  int ct = (v == 11) ? 1 : (v == 12) ? 2 : (v == 13) ? 3 : 0;
#pragma unroll
  for (int i = 0; i < 16; ++i) e[i] = val_emb[v * 16 + i];
#pragma unroll
  for (int i = 0; i < 16; ++i) e[16 + i] = suit_emb[s * 16 + i];
#pragma unroll
  for (int i = 0; i < 8; ++i) e[i] += type_emb[ct * 8 + i];
}

// ---------------------------------------------------------------------------
// Precompute, grid 33 x 256 (unchanged).
// ---------------------------------------------------------------------------
__global__ __launch_bounds__(256) void precompute_kernel(
    const int* __restrict__ acards,
    const float* __restrict__ val_emb, const float* __restrict__ suit_emb,
    const float* __restrict__ type_emb,
    const float* __restrict__ ce_w1, const float* __restrict__ ce_b1,
    const float* __restrict__ ce_w2, const float* __restrict__ ce_b2,
    const float* __restrict__ as_w1, const float* __restrict__ as_b1,
    const float* __restrict__ cx_w3, const float* __restrict__ cx_b3,
    const float* __restrict__ atc_w1, const float* __restrict__ atc_b1,
    float* __restrict__ ws) {
  const int tid = threadIdx.x;
  const int bid = blockIdx.x;

  if (bid > 0) {
    const int idx = (bid - 1) * 256 + tid;
    const int k = idx >> 6, j = idx & 63;
    float at = 0.f, ap = 0.f;
#pragma unroll 8
    for (int m = 0; m < 128; ++m) {
      float c = cx_w3[k * 128 + m];
      at += c * atc_w1[m * 64 + j];
      ap += c * as_w1[(size_t)m * 64 + j];
    }
    ws[2048 + idx] = at;
    ws[10304 + idx] = ap;
    return;
  }

  __shared__ float sAct[30][32];
  __shared__ float sCombo[30][16];

  if (tid >= 64 && tid < 128) {
    const int j = tid - 64;
    float bt = atc_b1[j], bp = 0.f;
#pragma unroll 8
    for (int m = 0; m < 128; ++m) {
      float c = cx_b3[m];
      bt += c * atc_w1[m * 64 + j];
      bp += c * as_w1[(size_t)m * 64 + j];
    }
    ws[10240 + j] = bt;
    ws[18496 + j] = bp;
  }

  if (tid < 30) {
    int c[4];
#pragma unroll
    for (int i = 0; i < 4; ++i) c[i] = acards[tid * 4 + i];
    bool mask[4]; int vals[4], suits[4]; int csize = 0; bool hasv = false;
#pragma unroll
    for (int i = 0; i < 4; ++i) {
      mask[i] = (c[i] != 0);
      if (mask[i]) { csize++; hasv = true; }
      vals[i] = mask[i] ? ((c[i] - 1) % 13 + 1) : 0;
      suits[i] = mask[i] ? ((c[i] - 1) / 13 + 1) : 0;
    }
    int fvv = mask[0] ? vals[0] : mask[1] ? vals[1] : mask[2] ? vals[2]
              : mask[3] ? vals[3] : vals[0];
    bool same = true;
#pragma unroll
    for (int i = 0; i < 4; ++i) if (mask[i] && vals[i] != fvv) same = false;
    float total = 0.f;
#pragma unroll
    for (int i = 0; i < 4; ++i) {
      if (mask[i]) {
        int v = vals[i];
        total += (v == 1) ? 1.f : (v == 11) ? 10.f : (v == 12) ? 15.f
                 : (v == 13) ? 20.f : (float)v;
      }
    }
    float uniq = 0.f;
#pragma unroll
    for (int s = 1; s <= 4; ++s) {
      bool any = false;
#pragma unroll
      for (int i = 0; i < 4; ++i) if (suits[i] == s) any = true;
      uniq += any ? 1.f : 0.f;
    }
    bool ace = false;
#pragma unroll
    for (int i = 0; i < 4; ++i) if (mask[i] && vals[i] == 1) ace = true;
    float f_same = same ? 1.f : 0.f, f_ace = ace ? 1.f : 0.f;
    float valid = (((float)csize <= 4.f) && (f_same > 0.f || f_ace > 0.f)) ? 1.f : 0.f;
    float feats[6] = {(float)csize, f_same, total, uniq, f_ace, valid};
    if (!hasv) { for (int i = 0; i < 6; ++i) feats[i] = 0.f; }
    float emb[32];
#pragma unroll
    for (int i = 0; i < 32; ++i) emb[i] = 0.f;
    float cnt = 0.f;
#pragma unroll
    for (int i = 0; i < 4; ++i) {
      float e[32];
      encode_card32(c[i], val_emb, suit_emb, type_emb, e);
      if (mask[i]) {
#pragma unroll
        for (int j = 0; j < 32; ++j) emb[j] += e[j];
        cnt += 1.f;
      }
    }
    float invc = 1.f / fmaxf(cnt, 1.f);
#pragma unroll
    for (int j = 0; j < 32; ++j) sAct[tid][j] = hasv ? emb[j] * invc : 0.f;
    float t32[32];
#pragma unroll
    for (int j = 0; j < 32; ++j) {
      float acc = ce_b1[j];
#pragma unroll
      for (int k = 0; k < 6; ++k) acc += feats[k] * ce_w1[k * 32 + j];
      t32[j] = fmaxf(acc, 0.f);
    }
#pragma unroll
    for (int j = 0; j < 16; ++j) {
      float acc = ce_b2[j];
#pragma unroll
      for (int k = 0; k < 32; ++k) acc += t32[k] * ce_w2[k * 16 + j];
      sCombo[tid][j] = acc;
    }
    ws[1920 + tid] = total * 0.05f;
    ws[1950 + tid] = hasv ? 1.f : 0.f;
  }
  __syncthreads();
  for (int idx = tid; idx < 1920; idx += 256) {
    int a = idx >> 6, j = idx & 63;
    float acc = as_b1[j];
#pragma unroll
    for (int k = 0; k < 32; ++k) acc += sAct[a][k] * as_w1[(128 + k) * 64 + j];
#pragma unroll
    for (int k = 0; k < 16; ++k) acc += sCombo[a][k] * as_w1[(160 + k) * 64 + j];
    ws[idx] = acc;
  }
}

// ---------------------------------------------------------------------------
// layerU for the SMALL phases only (A/B): wave-uniform s_load weights.
// ---------------------------------------------------------------------------
template <int K, int NJ, bool RELU, bool HASB, bool QIN, bool QOUT>
__device__ __forceinline__ void layerU(
    const float* __restrict__ in, int inColBase, float* __restrict__ outB,
    int outColBase, const float* __restrict__ W, int ldw, int j0,
    const float* __restrict__ bias, int r) {
  float acc[NJ];
#pragma unroll
  for (int j = 0; j < NJ; ++j) acc[j] = HASB ? bias[j0 + j] : 0.f;
  if constexpr (QIN) {
    static_assert(K % 4 == 0, "quad input needs K%4==0");
    const int g0 = inColBase >> 2;
#pragma unroll 8
    for (int g = 0; g < K / 4; ++g) {
      float4 a = *(const float4*)&in[(g0 + g) * 256 + r * 4];
#pragma unroll
      for (int q = 0; q < 4; ++q) {
        float av = (q == 0) ? a.x : (q == 1) ? a.y : (q == 2) ? a.z : a.w;
        const float* wr = W + (size_t)(g * 4 + q) * ldw + j0;
#pragma unroll
        for (int j = 0; j < NJ; ++j) acc[j] += av * wr[j];
      }
    }
  } else {
#pragma unroll 4
    for (int k = 0; k < K; ++k) {
      float a = in[(inColBase + k) * 64 + r];
      const float* wr = W + (size_t)k * ldw + j0;
#pragma unroll
      for (int j = 0; j < NJ; ++j) acc[j] += a * wr[j];
    }
  }
#pragma unroll
  for (int j = 0; j < NJ; ++j) if (RELU) acc[j] = fmaxf(acc[j], 0.f);
  if constexpr (QOUT && (NJ % 4 == 0)) {
    const int c0 = outColBase + j0;
#pragma unroll
    for (int qg = 0; qg < NJ / 4; ++qg) {
      float4 o = make_float4(acc[qg * 4], acc[qg * 4 + 1],
                             acc[qg * 4 + 2], acc[qg * 4 + 3]);
      *(float4*)&outB[((c0 >> 2) + qg) * 256 + r * 4] = o;
    }
  } else {
#pragma unroll
    for (int j = 0; j < NJ; ++j) outB[(outColBase + j0 + j) * 64 + r] = acc[j];
  }
}

// ---------------------------------------------------------------------------
// Main kernel. 64 rows/block, 1024 threads (16 waves), grid 256.
// bufA (quad, 152 cols): [0:32) hand_ctx | [32:64) enemy | [64:96) strat_ctx |
//   [96:150) discard -> later h2 (quads 0..31) -> coef [0:192)
// bufB: rows [0:20) strat_in | [20:84) t64 | [84:116) V | 116 sLen
//   -> quad h1 -> P7 out: t1 quads 0..15 | P quads 16..31
// wbuf: cx_w1 (19200 f) -> cx_w2 (16384 f) -> W_t1 [0:8192) | W_P [8192:16384)
// abuf: as_w2 (2048 f), loaded at top, never overwritten.
// ---------------------------------------------------------------------------
__global__ __launch_bounds__(1024) void policy_main(
    const int* __restrict__ hand_cards, const int* __restrict__ enemy_card,
    const int* __restrict__ hand_size, const float* __restrict__ game_state,
    const float* __restrict__ discard,
    const float* __restrict__ val_emb, const float* __restrict__ suit_emb,
    const float* __restrict__ type_emb,
    const float* __restrict__ he_wv, const float* __restrict__ he_bv,
    const float* __restrict__ he_wo, const float* __restrict__ he_bo,
    const float* __restrict__ se_w1, const float* __restrict__ se_b1,
    const float* __restrict__ se_w2, const float* __restrict__ se_b2,
    const float* __restrict__ atc_w2, const float* __restrict__ atc_b2,
    const float* __restrict__ as_w2, const float* __restrict__ as_b2,
    const float* __restrict__ as_w3, const float* __restrict__ as_b3,
    const float* __restrict__ cx_w1, const float* __restrict__ cx_b1,
    const float* __restrict__ cx_w2, const float* __restrict__ cx_b2,
    const float* __restrict__ ws, float* __restrict__ out) {
  __shared__ float bufA[38 * 256];   // 38 KB
  __shared__ float bufB[128 * 64];   // 32 KB
  __shared__ float wbuf[19200];      // 76.8 KB weight stage
  __shared__ float abuf[2048];       // 8 KB as_w2

  const int tid = threadIdx.x;
  const int r = tid & 63;                                   // lane = batch row
  const int wq = __builtin_amdgcn_readfirstlane(tid >> 6);  // wave id 0..15
  const int b0 = blockIdx.x * 64;

  // ---- stage issue #1: cx_w1 + as_w2 -> LDS DMA (covered by P0/A/B) --------
#pragma unroll
  for (int i = 0; i < 4; ++i)
    glds16(cx_w1 + (size_t)(tid + i * 1024) * 4, &wbuf[(wq * 64 + i * 1024) * 4]);
  if (wq < 11)                                   // quads 4096..4799 (11 waves)
    glds16(cx_w1 + (size_t)(4096 + tid) * 4, &wbuf[(4096 + wq * 64) * 4]);
  if (wq < 8)                                    // as_w2: 512 quads
    glds16(as_w2 + (size_t)tid * 4, &abuf[wq * 256]);

  // ---------------- P0: staging + per-row features --------------------------
  for (int idx = tid; idx < 64 * 54; idx += 1024) {          // discard -> bufA
    int rr = idx / 54, k = idx - rr * 54;
    int c = 96 + k;
    bufA[(c >> 2) * 256 + rr * 4 + (c & 3)] = discard[(size_t)b0 * 54 + idx];
  }
  if (wq == 2) {                                            // game_state rows 0..9
#pragma unroll
    for (int k = 0; k < 10; ++k)
      bufB[k * 64 + r] = game_state[(size_t)(b0 + r) * 10 + k];
  }
  if (wq == 0) {                                            // hand features rows 10..19
    const int b = b0 + r;
    const float hsz = (float)hand_size[b];
    int aces = 0, faces = 0, low = 0, c1 = 0, c2 = 0, c3 = 0, c4 = 0;
#pragma unroll
    for (int i = 0; i < 8; ++i) {
      int c = hand_cards[b * 8 + i];
      int v = (c == 0) ? 0 : ((c - 1) % 13 + 1);
      int s = (c == 0) ? 0 : ((c - 1) / 13 + 1);
      aces += (v == 1);
      faces += (v >= 11 && v <= 13);
      low += (v >= 2 && v <= 6);
      c1 += (s == 1); c2 += (s == 2); c3 += (s == 3); c4 += (s == 4);
    }
    float sdiv = (float)((c1 > 0) + (c2 > 0) + (c3 > 0) + (c4 > 0)) * 0.25f;
    float hvr = (float)faces / (hsz + 1e-8f);
    bufB[(10 + 0) * 64 + r] = hsz;          bufB[(10 + 1) * 64 + r] = (float)aces;
    bufB[(10 + 2) * 64 + r] = (float)faces; bufB[(10 + 3) * 64 + r] = (float)low;
    bufB[(10 + 4) * 64 + r] = (float)c1;    bufB[(10 + 5) * 64 + r] = (float)c2;
    bufB[(10 + 6) * 64 + r] = (float)c3;    bufB[(10 + 7) * 64 + r] = (float)c4;
    bufB[(10 + 8) * 64 + r] = hvr;          bufB[(10 + 9) * 64 + r] = sdiv;
  }
  if (wq == 1) {                                            // enemy (quad) + sLen
    const int b = b0 + r;
    bufB[116 * 64 + r] = 8.0f / fmaxf((float)hand_size[b], 1.0f);
    float e[32];
    encode_card32(enemy_card[b], val_emb, suit_emb, type_emb, e);
#pragma unroll
    for (int g = 0; g < 8; ++g) {
      float4 ev = make_float4(e[g * 4], e[g * 4 + 1], e[g * 4 + 2], e[g * 4 + 3]);
      *(float4*)&bufA[(8 + g) * 256 + r * 4] = ev;   // cols 32..63
    }
  }
  __syncthreads();

  // ---------------- Phase A (task-parallel): se L1 | V -----------------------
  if (wq < 8) {
    layerU<20, 8, true, true, false, false>(bufB, 0, bufB, 20, se_w1, 64,
                                            wq * 8, se_b1, r);
  } else {
    layerU<32, 4, false, true, true, false>(bufA, 32, bufB, 84, he_wv, 32,
                                            (wq - 8) * 4, he_bv, r);
  }
  __syncthreads();

  // ---------------- Phase B (task-parallel): se L2 | hand_ctx ----------------
  if (wq < 8) {
    layerU<64, 4, false, true, false, true>(bufB, 20, bufA, 64, se_w2, 32,
                                            wq * 4, se_b2, r);
  } else {
    const int j0 = (wq - 8) * 4;
    float acc[4];
#pragma unroll
    for (int j = 0; j < 4; ++j) acc[j] = he_bo[j0 + j];
#pragma unroll 4
    for (int k = 0; k < 32; ++k) {
      float a = bufB[(84 + k) * 64 + r];
      const float* wr = he_wo + (size_t)k * 32 + j0;
#pragma unroll
      for (int j = 0; j < 4; ++j) acc[j] += a * wr[j];
    }
    float scale = bufB[116 * 64 + r];
    float4 o = make_float4(scale * acc[0], scale * acc[1],
                           scale * acc[2], scale * acc[3]);
    *(float4*)&bufA[(j0 >> 2) * 256 + r * 4] = o;
  }
  __syncthreads();   // drains vmcnt -> cx_w1/as_w2 DMA landed

  // ---------------- L1: 150->128 relu, weights from wbuf (LDS) --------------
  {
    const int j0 = wq * 8;
    float acc[8];
#pragma unroll
    for (int j = 0; j < 8; ++j) acc[j] = cx_b1[j0 + j];
#pragma unroll 8
    for (int g = 0; g < 37; ++g) {
      float4 a = *(const float4*)&bufA[g * 256 + r * 4];
#pragma unroll
      for (int q = 0; q < 4; ++q) {
        float av = (q == 0) ? a.x : (q == 1) ? a.y : (q == 2) ? a.z : a.w;
        const float* wr = &wbuf[(g * 4 + q) * 128 + j0];
        float4 w0 = ld4(wr), w1 = ld4(wr + 4);
        acc[0] += av * w0.x; acc[1] += av * w0.y;
        acc[2] += av * w0.z; acc[3] += av * w0.w;
        acc[4] += av * w1.x; acc[5] += av * w1.y;
        acc[6] += av * w1.z; acc[7] += av * w1.w;
      }
    }
    {  // tail: cols 148,149
      float4 a = *(const float4*)&bufA[37 * 256 + r * 4];
      const float* wr0 = &wbuf[148 * 128 + j0];
      const float* wr1 = &wbuf[149 * 128 + j0];
      float4 x0 = ld4(wr0), x1 = ld4(wr0 + 4);
      float4 y0 = ld4(wr1), y1 = ld4(wr1 + 4);
      acc[0] += a.x * x0.x + a.y * y0.x; acc[1] += a.x * x0.y + a.y * y0.y;
      acc[2] += a.x * x0.z + a.y * y0.z; acc[3] += a.x * x0.w + a.y * y0.w;
      acc[4] += a.x * x1.x + a.y * y1.x; acc[5] += a.x * x1.y + a.y * y1.y;
      acc[6] += a.x * x1.z + a.y * y1.z; acc[7] += a.x * x1.w + a.y * y1.w;
    }
#pragma unroll
    for (int qg = 0; qg < 2; ++qg) {
      float4 o = make_float4(fmaxf(acc[qg * 4], 0.f), fmaxf(acc[qg * 4 + 1], 0.f),
                             fmaxf(acc[qg * 4 + 2], 0.f), fmaxf(acc[qg * 4 + 3], 0.f));
      *(float4*)&bufB[((j0 >> 2) + qg) * 256 + r * 4] = o;   // h1 quad
    }
  }
  __syncthreads();   // all waves done reading cx_w1

  // ---- stage issue #2: cx_w2 -> wbuf DMA -----------------------------------
#pragma unroll
  for (int i = 0; i < 4; ++i)
    glds16(cx_w2 + (size_t)(tid + i * 1024) * 4, &wbuf[(wq * 64 + i * 1024) * 4]);
  __syncthreads();   // drains vmcnt -> cx_w2 landed (~1us exposed)

  // ---------------- L2: 128->128 relu, weights from wbuf (LDS) --------------
  {
    const int j0 = wq * 8;
    float acc[8];
#pragma unroll
    for (int j = 0; j < 8; ++j) acc[j] = cx_b2[j0 + j];
#pragma unroll 8
    for (int g = 0; g < 32; ++g) {
      float4 a = *(const float4*)&bufB[g * 256 + r * 4];
#pragma unroll
      for (int q = 0; q < 4; ++q) {
        float av = (q == 0) ? a.x : (q == 1) ? a.y : (q == 2) ? a.z : a.w;
        const float* wr = &wbuf[(g * 4 + q) * 128 + j0];
        float4 w0 = ld4(wr), w1 = ld4(wr + 4);
        acc[0] += av * w0.x; acc[1] += av * w0.y;
        acc[2] += av * w0.z; acc[3] += av * w0.w;
        acc[4] += av * w1.x; acc[5] += av * w1.y;
        acc[6] += av * w1.z; acc[7] += av * w1.w;
      }
    }
#pragma unroll
    for (int qg = 0; qg < 2; ++qg) {
      float4 o = make_float4(fmaxf(acc[qg * 4], 0.f), fmaxf(acc[qg * 4 + 1], 0.f),
                             fmaxf(acc[qg * 4 + 2], 0.f), fmaxf(acc[qg * 4 + 3], 0.f));
      *(float4*)&bufA[((j0 >> 2) + qg) * 256 + r * 4] = o;   // h2 quad
    }
  }
  __syncthreads();   // all waves done reading cx_w2

  // ---- stage issue #3: W_t1 | W_P -> wbuf DMA ------------------------------
#pragma unroll
  for (int i = 0; i < 2; ++i) {
    glds16(ws + 2048 + (size_t)(tid + i * 1024) * 4,
           &wbuf[(wq * 64 + i * 1024) * 4]);
    glds16(ws + 10304 + (size_t)(tid + i * 1024) * 4,
           &wbuf[8192 + (wq * 64 + i * 1024) * 4]);
  }
  __syncthreads();   // drains vmcnt -> W_t1/W_P landed

  // ---------------- P7 (L3 folded): t1 | P from h2, weights in wbuf ---------
  {
    const bool isT = (wq < 8);
    const int j0 = (wq & 7) * 8;
    const float* W = isT ? wbuf : (wbuf + 8192);
    const float* Bb = isT ? (ws + 10240) : (ws + 18496);
    float acc[8];
#pragma unroll
    for (int j = 0; j < 8; ++j) acc[j] = Bb[j0 + j];
#pragma unroll 8
    for (int g = 0; g < 32; ++g) {
      float4 a = *(const float4*)&bufA[g * 256 + r * 4];
#pragma unroll
      for (int q = 0; q < 4; ++q) {
        float av = (q == 0) ? a.x : (q == 1) ? a.y : (q == 2) ? a.z : a.w;
        const float* wr = W + (g * 4 + q) * 64 + j0;
        float4 w0 = ld4(wr), w1 = ld4(wr + 4);
        acc[0] += av * w0.x; acc[1] += av * w0.y;
        acc[2] += av * w0.z; acc[3] += av * w0.w;
        acc[4] += av * w1.x; acc[5] += av * w1.y;
        acc[6] += av * w1.z; acc[7] += av * w1.w;
      }
    }
    if (isT) {
#pragma unroll
      for (int j = 0; j < 8; ++j) acc[j] = fmaxf(acc[j], 0.f);
    }
    const int c0 = (isT ? 0 : 64) + j0;
#pragma unroll
    for (int qg = 0; qg < 2; ++qg) {
      float4 o = make_float4(acc[qg * 4], acc[qg * 4 + 1],
                             acc[qg * 4 + 2], acc[qg * 4 + 3]);
      *(float4*)&bufB[((c0 >> 2) + qg) * 256 + r * 4] = o;
    }
  }
  __syncthreads();

  // ---------------- P9: wave15 probs | waves 0-14 fused 2-action MLP --------
  // as_w2 from abuf (LDS, loaded at top); Qa wave-uniform s_load (R16-proven).
  float acc0[32], acc1[32];
  if (wq == 15) {
    float lg0 = atc_b2[0], lg1 = atc_b2[1], lg2 = atc_b2[2], lg3 = atc_b2[3];
#pragma unroll 4
    for (int g = 0; g < 16; ++g) {            // t1 = bufB quads 0..15
      float4 t = *(const float4*)&bufB[g * 256 + r * 4];
#pragma unroll
      for (int q = 0; q < 4; ++q) {
        float tv = (q == 0) ? t.x : (q == 1) ? t.y : (q == 2) ? t.z : t.w;
        const float* wr = atc_w2 + (size_t)(g * 4 + q) * 4;
        lg0 += tv * wr[0]; lg1 += tv * wr[1];
        lg2 += tv * wr[2]; lg3 += tv * wr[3];
      }
    }
    float m = fmaxf(fmaxf(lg0, lg1), fmaxf(lg2, lg3));
    float e0 = expf(lg0 - m), e1 = expf(lg1 - m), e2 = expf(lg2 - m), e3 = expf(lg3 - m);
    float inv = 1.f / (e0 + e1 + e2 + e3);
    bufA[r]       = (e0 - e1) * inv;   // tp0 - tp1
    bufA[64 + r]  = e1 * inv;          // tp1
    bufA[128 + r] = 2.f * e3 * inv;    // 2 * tp3
  } else {
    const int a0 = wq * 2;
    const float* qa = ws + a0 * 64;            // uniform -> s_load
#pragma unroll
    for (int j = 0; j < 32; ++j) { acc0[j] = 0.f; acc1[j] = 0.f; }
#pragma unroll 4
    for (int g = 0; g < 16; ++g) {             // P = bufB quads 16..31
      float4 pv = *(const float4*)&bufB[(16 + g) * 256 + r * 4];
#pragma unroll
      for (int q = 0; q < 4; ++q) {
        float p = (q == 0) ? pv.x : (q == 1) ? pv.y : (q == 2) ? pv.z : pv.w;
        const int k = g * 4 + q;
        float s0 = fmaxf(p + qa[k], 0.f);
        float s1 = fmaxf(p + qa[64 + k], 0.f);
        const float* w2r = &abuf[k * 32];
#pragma unroll
        for (int jq = 0; jq < 8; ++jq) {
          float4 w = ld4(w2r + jq * 4);
          acc0[jq * 4 + 0] += s0 * w.x; acc1[jq * 4 + 0] += s1 * w.x;
          acc0[jq * 4 + 1] += s0 * w.y; acc1[jq * 4 + 1] += s1 * w.y;
          acc0[jq * 4 + 2] += s0 * w.z; acc1[jq * 4 + 2] += s1 * w.z;
          acc0[jq * 4 + 3] += s0 * w.w; acc1[jq * 4 + 3] += s1 * w.w;
        }
      }
    }
  }
  __syncthreads();   // waves 0-14 arrive late; only wave 15 really waits

  if (wq < 15) {
    const int a0 = wq * 2;
    const float b3v = as_b3[0];
    float sc0 = b3v, sc1 = b3v;
#pragma unroll
    for (int j = 0; j < 32; ++j) {
      float b2 = as_b2[j], w3 = as_w3[j];
      sc0 += fmaxf(acc0[j] + b2, 0.f) * w3;
      sc1 += fmaxf(acc1[j] + b2, 0.f) * w3;
    }
    float da = bufA[r], t1b = bufA[64 + r], t3x2 = bufA[128 + r];
    float st0 = ws[1920 + a0], hv0 = ws[1950 + a0];
    float st1 = ws[1921 + a0], hv1 = ws[1951 + a0];
    float bon0 = (hv0 > 0.5f) ? (t1b + st0 * da) : t3x2;
    float bon1 = (hv1 > 0.5f) ? (t1b + st1 * da) : t3x2;
    *(float2*)&out[(size_t)(b0 + r) * 30 + a0] =
        make_float2(sc0 + bon0, sc1 + bon1);
  }
}

// ---------------------------------------------------------------------------
extern "C" void kernel_launch(void* const* d_in, const int* in_sizes, int n_in,
                              void* d_out, int out_size, void* d_ws, size_t ws_size,
                              hipStream_t stream) {
  (void)in_sizes; (void)n_in; (void)out_size; (void)ws_size;
  const int* hand_cards = (const int*)d_in[0];
  const int* enemy_card = (const int*)d_in[1];
  const int* hand_size = (const int*)d_in[2];
  const float* game_state = (const float*)d_in[3];
  const float* discard = (const float*)d_in[4];
  const int* acards = (const int*)d_in[5];
  // d_in[6] = num_valid_actions (unused scalar)
  const float* val_emb = (const float*)d_in[7];
  const float* suit_emb = (const float*)d_in[8];
  const float* type_emb = (const float*)d_in[9];
  const float* ce_w1 = (const float*)d_in[10], * ce_b1 = (const float*)d_in[11];
  const float* ce_w2 = (const float*)d_in[12], * ce_b2 = (const float*)d_in[13];
  // d_in[14..21] = ha_* (hand self-attention) -- provably dead code, unused
  const float* he_wv = (const float*)d_in[26], * he_bv = (const float*)d_in[27];
  const float* he_wo = (const float*)d_in[28], * he_bo = (const float*)d_in[29];
  const float* se_w1 = (const float*)d_in[30], * se_b1 = (const float*)d_in[31];
  const float* se_w2 = (const float*)d_in[32], * se_b2 = (const float*)d_in[33];
  const float* atc_w1 = (const float*)d_in[34], * atc_b1 = (const float*)d_in[35];
  const float* atc_w2 = (const float*)d_in[36], * atc_b2 = (const float*)d_in[37];
  const float* as_w1 = (const float*)d_in[38], * as_b1 = (const float*)d_in[39];
  const float* as_w2 = (const float*)d_in[40], * as_b2 = (const float*)d_in[41];
  const float* as_w3 = (const float*)d_in[42], * as_b3 = (const float*)d_in[43];
  const float* cx_w1 = (const float*)d_in[44], * cx_b1 = (const float*)d_in[45];
  const float* cx_w2 = (const float*)d_in[46], * cx_b2 = (const float*)d_in[47];
  const float* cx_w3 = (const float*)d_in[48], * cx_b3 = (const float*)d_in[49];
  float* ws = (float*)d_ws;
  float* out = (float*)d_out;

  hipLaunchKernelGGL(precompute_kernel, dim3(33), dim3(256), 0, stream,
                     acards, val_emb, suit_emb, type_emb,
                     ce_w1, ce_b1, ce_w2, ce_b2, as_w1, as_b1,
                     cx_w3, cx_b3, atc_w1, atc_b1, ws);
  hipLaunchKernelGGL(policy_main, dim3(256), dim3(1024), 0, stream,
                     hand_cards, enemy_card, hand_size, game_state, discard,
                     val_emb, suit_emb, type_emb,
                     he_wv, he_bv, he_wo, he_bo,
                     se_w1, se_b1, se_w2, se_b2,
                     atc_w2, atc_b2,
                     as_w2, as_b2, as_w3, as_b3,
                     cx_w1, cx_b1, cx_w2, cx_b2,
                     ws, out);
}

// Round 8
// 232.791 us; speedup vs baseline: 1.1105x; 1.1105x over previous
//
#include <hip/hip_runtime.h>
#include <math.h>

// ---------------------------------------------------------------------------
// R23 = R16 exactly (75us proven: s_load weight streams, P9 2-action fusion,
// wave15 logits dedup, L3 folded into P7) + PACKED FP32 FMA in the hot loops.
// Rationale: R19-R22 proved any VGPR-routed weight path spills at 16 waves/CU
// (128 VGPR/wave unified budget; weights must stay in SGPRs). R16 is the
// right memory structure. But MI355X's 157 TF fp32 assumes v_pk_fma_f32
// (VOP3P, 2 FLOP/lane/instr); scalar v_fma caps at 78.6 TF -> R16's 75us sits
// near the SCALAR issue floor (~48us). Packed math halves FMA instruction
// count in L1/L2/P7/P9 at zero register cost: accs become float2 pairs
// (same storage), weights load as uniform float2 (s_load_dwordx2, SGPR-pair
// source is legal in VOP3P). clang contracts a*b+c on ext_vector_type(2)
// to llvm.fma.v2f32 -> v_pk_fma_f32 on gfx950.
// Everything else byte-identical to R16. LDS 71680, grid 256, 1024 thr.
// ws layout (floats): [0:1920) Qa | [1920:1950) strength | [1950:1980) hasv |
//   [2048:10240) W_t1 | [10240:10304) b_t1 | [10304:18496) W_P | [18496:18560) b_P
// ---------------------------------------------------------------------------

typedef float float2v __attribute__((ext_vector_type(2)));

__device__ __forceinline__ void encode_card32(int c,
                                              const float* __restrict__ val_emb,
                                              const float* __restrict__ suit_emb,
                                              const float* __restrict__ type_emb,
                                              float* e) {
  bool inv = (c == 0) || (c == 53);
  int v = inv ? 0 : ((c - 1) % 13 + 1);
  int s = inv ? 0 : ((c - 1) / 13 + 1);
  int ct = (v == 11) ? 1 : (v == 12) ? 2 : (v == 13) ? 3 : 0;
#pragma unroll
  for (int i = 0; i < 16; ++i) e[i] = val_emb[v * 16 + i];
#pragma unroll
  for (int i = 0; i < 16; ++i) e[16 + i] = suit_emb[s * 16 + i];
#pragma unroll
  for (int i = 0; i < 8; ++i) e[i] += type_emb[ct * 8 + i];
}

// ---------------------------------------------------------------------------
// Precompute, grid 33 x 256 (unchanged).
// ---------------------------------------------------------------------------
__global__ __launch_bounds__(256) void precompute_kernel(
    const int* __restrict__ acards,
    const float* __restrict__ val_emb, const float* __restrict__ suit_emb,
    const float* __restrict__ type_emb,
    const float* __restrict__ ce_w1, const float* __restrict__ ce_b1,
    const float* __restrict__ ce_w2, const float* __restrict__ ce_b2,
    const float* __restrict__ as_w1, const float* __restrict__ as_b1,
    const float* __restrict__ cx_w3, const float* __restrict__ cx_b3,
    const float* __restrict__ atc_w1, const float* __restrict__ atc_b1,
    float* __restrict__ ws) {
  const int tid = threadIdx.x;
  const int bid = blockIdx.x;

  if (bid > 0) {
    const int idx = (bid - 1) * 256 + tid;
    const int k = idx >> 6, j = idx & 63;
    float at = 0.f, ap = 0.f;
#pragma unroll 8
    for (int m = 0; m < 128; ++m) {
      float c = cx_w3[k * 128 + m];
      at += c * atc_w1[m * 64 + j];
      ap += c * as_w1[(size_t)m * 64 + j];
    }
    ws[2048 + idx] = at;
    ws[10304 + idx] = ap;
    return;
  }

  __shared__ float sAct[30][32];
  __shared__ float sCombo[30][16];

  if (tid >= 64 && tid < 128) {
    const int j = tid - 64;
    float bt = atc_b1[j], bp = 0.f;
#pragma unroll 8
    for (int m = 0; m < 128; ++m) {
      float c = cx_b3[m];
      bt += c * atc_w1[m * 64 + j];
      bp += c * as_w1[(size_t)m * 64 + j];
    }
    ws[10240 + j] = bt;
    ws[18496 + j] = bp;
  }

  if (tid < 30) {
    int c[4];
#pragma unroll
    for (int i = 0; i < 4; ++i) c[i] = acards[tid * 4 + i];
    bool mask[4]; int vals[4], suits[4]; int csize = 0; bool hasv = false;
#pragma unroll
    for (int i = 0; i < 4; ++i) {
      mask[i] = (c[i] != 0);
      if (mask[i]) { csize++; hasv = true; }
      vals[i] = mask[i] ? ((c[i] - 1) % 13 + 1) : 0;
      suits[i] = mask[i] ? ((c[i] - 1) / 13 + 1) : 0;
    }
    int fvv = mask[0] ? vals[0] : mask[1] ? vals[1] : mask[2] ? vals[2]
              : mask[3] ? vals[3] : vals[0];
    bool same = true;
#pragma unroll
    for (int i = 0; i < 4; ++i) if (mask[i] && vals[i] != fvv) same = false;
    float total = 0.f;
#pragma unroll
    for (int i = 0; i < 4; ++i) {
      if (mask[i]) {
        int v = vals[i];
        total += (v == 1) ? 1.f : (v == 11) ? 10.f : (v == 12) ? 15.f
                 : (v == 13) ? 20.f : (float)v;
      }
    }
    float uniq = 0.f;
#pragma unroll
    for (int s = 1; s <= 4; ++s) {
      bool any = false;
#pragma unroll
      for (int i = 0; i < 4; ++i) if (suits[i] == s) any = true;
      uniq += any ? 1.f : 0.f;
    }
    bool ace = false;
#pragma unroll
    for (int i = 0; i < 4; ++i) if (mask[i] && vals[i] == 1) ace = true;
    float f_same = same ? 1.f : 0.f, f_ace = ace ? 1.f : 0.f;
    float valid = (((float)csize <= 4.f) && (f_same > 0.f || f_ace > 0.f)) ? 1.f : 0.f;
    float feats[6] = {(float)csize, f_same, total, uniq, f_ace, valid};
    if (!hasv) { for (int i = 0; i < 6; ++i) feats[i] = 0.f; }
    float emb[32];
#pragma unroll
    for (int i = 0; i < 32; ++i) emb[i] = 0.f;
    float cnt = 0.f;
#pragma unroll
    for (int i = 0; i < 4; ++i) {
      float e[32];
      encode_card32(c[i], val_emb, suit_emb, type_emb, e);
      if (mask[i]) {
#pragma unroll
        for (int j = 0; j < 32; ++j) emb[j] += e[j];
        cnt += 1.f;
      }
    }
    float invc = 1.f / fmaxf(cnt, 1.f);
#pragma unroll
    for (int j = 0; j < 32; ++j) sAct[tid][j] = hasv ? emb[j] * invc : 0.f;
    float t32[32];
#pragma unroll
    for (int j = 0; j < 32; ++j) {
      float acc = ce_b1[j];
#pragma unroll
      for (int k = 0; k < 6; ++k) acc += feats[k] * ce_w1[k * 32 + j];
      t32[j] = fmaxf(acc, 0.f);
    }
#pragma unroll
    for (int j = 0; j < 16; ++j) {
      float acc = ce_b2[j];
#pragma unroll
      for (int k = 0; k < 32; ++k) acc += t32[k] * ce_w2[k * 16 + j];
      sCombo[tid][j] = acc;
    }
    ws[1920 + tid] = total * 0.05f;
    ws[1950 + tid] = hasv ? 1.f : 0.f;
  }
  __syncthreads();
  for (int idx = tid; idx < 1920; idx += 256) {
    int a = idx >> 6, j = idx & 63;
    float acc = as_b1[j];
#pragma unroll
    for (int k = 0; k < 32; ++k) acc += sAct[a][k] * as_w1[(128 + k) * 64 + j];
#pragma unroll
    for (int k = 0; k < 16; ++k) acc += sCombo[a][k] * as_w1[(160 + k) * 64 + j];
    ws[idx] = acc;
  }
}

// ---------------------------------------------------------------------------
// layerU (scalar, R16 verbatim) for the SMALL phases A/B only.
// ---------------------------------------------------------------------------
template <int K, int NJ, bool RELU, bool HASB, bool QIN, bool QOUT>
__device__ __forceinline__ void layerU(
    const float* __restrict__ in, int inColBase, float* __restrict__ outB,
    int outColBase, const float* __restrict__ W, int ldw, int j0,
    const float* __restrict__ bias, int r) {
  float acc[NJ];
#pragma unroll
  for (int j = 0; j < NJ; ++j) acc[j] = HASB ? bias[j0 + j] : 0.f;
  if constexpr (QIN) {
    static_assert(K % 4 == 0, "quad input needs K%4==0");
    const int g0 = inColBase >> 2;
#pragma unroll 8
    for (int g = 0; g < K / 4; ++g) {
      float4 a = *(const float4*)&in[(g0 + g) * 256 + r * 4];
#pragma unroll
      for (int q = 0; q < 4; ++q) {
        float av = (q == 0) ? a.x : (q == 1) ? a.y : (q == 2) ? a.z : a.w;
        const float* wr = W + (size_t)(g * 4 + q) * ldw + j0;
#pragma unroll
        for (int j = 0; j < NJ; ++j) acc[j] += av * wr[j];
      }
    }
  } else {
#pragma unroll 4
    for (int k = 0; k < K; ++k) {
      float a = in[(inColBase + k) * 64 + r];
      const float* wr = W + (size_t)k * ldw + j0;
#pragma unroll
      for (int j = 0; j < NJ; ++j) acc[j] += a * wr[j];
    }
  }
#pragma unroll
  for (int j = 0; j < NJ; ++j) if (RELU) acc[j] = fmaxf(acc[j], 0.f);
  if constexpr (QOUT && (NJ % 4 == 0)) {
    const int c0 = outColBase + j0;
#pragma unroll
    for (int qg = 0; qg < NJ / 4; ++qg) {
      float4 o = make_float4(acc[qg * 4], acc[qg * 4 + 1],
                             acc[qg * 4 + 2], acc[qg * 4 + 3]);
      *(float4*)&outB[((c0 >> 2) + qg) * 256 + r * 4] = o;
    }
  } else {
#pragma unroll
    for (int j = 0; j < NJ; ++j) outB[(outColBase + j0 + j) * 64 + r] = acc[j];
  }
}

// ---------------------------------------------------------------------------
// layer128P: PACKED K=128, NJ=8 layer (quad in -> quad out). Weights stream
// wave-uniformly (s_load); FMAs are float2v -> v_pk_fma_f32. Used by L2/P7.
// ---------------------------------------------------------------------------
template <bool RELU>
__device__ __forceinline__ void layer128P(
    const float* __restrict__ in, float* __restrict__ outB, int outColBase,
    const float* __restrict__ W, int ldw, int j0,
    const float* __restrict__ bias, int r) {
  float2v A[4];
#pragma unroll
  for (int jp = 0; jp < 4; ++jp) A[jp] = *(const float2v*)&bias[j0 + jp * 2];
#pragma unroll 8
  for (int g = 0; g < 32; ++g) {
    float4 a = *(const float4*)&in[g * 256 + r * 4];
#pragma unroll
    for (int q = 0; q < 4; ++q) {
      float av = (q == 0) ? a.x : (q == 1) ? a.y : (q == 2) ? a.z : a.w;
      float2v av2 = {av, av};
      const float* wr = W + (size_t)(g * 4 + q) * ldw + j0;
#pragma unroll
      for (int jp = 0; jp < 4; ++jp) {
        float2v wv = *(const float2v*)&wr[jp * 2];
        A[jp] += av2 * wv;                       // v_pk_fma_f32
      }
    }
  }
  if (RELU) {
#pragma unroll
    for (int jp = 0; jp < 4; ++jp) {
      A[jp].x = fmaxf(A[jp].x, 0.f);
      A[jp].y = fmaxf(A[jp].y, 0.f);
    }
  }
  const int c0 = outColBase + j0;
#pragma unroll
  for (int qg = 0; qg < 2; ++qg) {
    float4 o = make_float4(A[qg * 2].x, A[qg * 2].y,
                           A[qg * 2 + 1].x, A[qg * 2 + 1].y);
    *(float4*)&outB[((c0 >> 2) + qg) * 256 + r * 4] = o;
  }
}

// ---------------------------------------------------------------------------
// Main kernel. 64 rows/block, 1024 threads (16 waves), grid 256. R16 layout:
// bufA (quad, 152 cols): [0:32) hand_ctx | [32:64) enemy | [64:96) strat_ctx |
//   [96:150) discard -> later h2 (128) -> later per-row prob coefs [0:192)
// bufB: rows [0:20) strat_in | [20:84) t64 | [84:116) V | 116 sLen
//   -> quad h1 -> P7 out: t1 quads 0..15 | P quads 16..31
// ---------------------------------------------------------------------------
__global__ __launch_bounds__(1024) void policy_main(
    const int* __restrict__ hand_cards, const int* __restrict__ enemy_card,
    const int* __restrict__ hand_size, const float* __restrict__ game_state,
    const float* __restrict__ discard,
    const float* __restrict__ val_emb, const float* __restrict__ suit_emb,
    const float* __restrict__ type_emb,
    const float* __restrict__ he_wv, const float* __restrict__ he_bv,
    const float* __restrict__ he_wo, const float* __restrict__ he_bo,
    const float* __restrict__ se_w1, const float* __restrict__ se_b1,
    const float* __restrict__ se_w2, const float* __restrict__ se_b2,
    const float* __restrict__ atc_w2, const float* __restrict__ atc_b2,
    const float* __restrict__ as_w2, const float* __restrict__ as_b2,
    const float* __restrict__ as_w3, const float* __restrict__ as_b3,
    const float* __restrict__ cx_w1, const float* __restrict__ cx_b1,
    const float* __restrict__ cx_w2, const float* __restrict__ cx_b2,
    const float* __restrict__ ws, float* __restrict__ out) {
  __shared__ float bufA[38 * 256];   // 38 KB
  __shared__ float bufB[128 * 64];   // 32 KB

  const int tid = threadIdx.x;
  const int r = tid & 63;                                   // lane = batch row
  const int wq = __builtin_amdgcn_readfirstlane(tid >> 6);  // wave id 0..15
  const int b0 = blockIdx.x * 64;

  // ---------------- P0: staging + per-row features --------------------------
  for (int idx = tid; idx < 64 * 54; idx += 1024) {          // discard -> bufA
    int rr = idx / 54, k = idx - rr * 54;
    int c = 96 + k;
    bufA[(c >> 2) * 256 + rr * 4 + (c & 3)] = discard[(size_t)b0 * 54 + idx];
  }
  if (wq == 2) {                                            // game_state rows 0..9
#pragma unroll
    for (int k = 0; k < 10; ++k)
      bufB[k * 64 + r] = game_state[(size_t)(b0 + r) * 10 + k];
  }
  if (wq == 0) {                                            // hand features rows 10..19
    const int b = b0 + r;
    const float hsz = (float)hand_size[b];
    int aces = 0, faces = 0, low = 0, c1 = 0, c2 = 0, c3 = 0, c4 = 0;
#pragma unroll
    for (int i = 0; i < 8; ++i) {
      int c = hand_cards[b * 8 + i];
      int v = (c == 0) ? 0 : ((c - 1) % 13 + 1);
      int s = (c == 0) ? 0 : ((c - 1) / 13 + 1);
      aces += (v == 1);
      faces += (v >= 11 && v <= 13);
      low += (v >= 2 && v <= 6);
      c1 += (s == 1); c2 += (s == 2); c3 += (s == 3); c4 += (s == 4);
    }
    float sdiv = (float)((c1 > 0) + (c2 > 0) + (c3 > 0) + (c4 > 0)) * 0.25f;
    float hvr = (float)faces / (hsz + 1e-8f);
    bufB[(10 + 0) * 64 + r] = hsz;          bufB[(10 + 1) * 64 + r] = (float)aces;
    bufB[(10 + 2) * 64 + r] = (float)faces; bufB[(10 + 3) * 64 + r] = (float)low;
    bufB[(10 + 4) * 64 + r] = (float)c1;    bufB[(10 + 5) * 64 + r] = (float)c2;
    bufB[(10 + 6) * 64 + r] = (float)c3;    bufB[(10 + 7) * 64 + r] = (float)c4;
    bufB[(10 + 8) * 64 + r] = hvr;          bufB[(10 + 9) * 64 + r] = sdiv;
  }
  if (wq == 1) {                                            // enemy (quad) + sLen
    const int b = b0 + r;
    bufB[116 * 64 + r] = 8.0f / fmaxf((float)hand_size[b], 1.0f);
    float e[32];
    encode_card32(enemy_card[b], val_emb, suit_emb, type_emb, e);
#pragma unroll
    for (int g = 0; g < 8; ++g) {
      float4 ev = make_float4(e[g * 4], e[g * 4 + 1], e[g * 4 + 2], e[g * 4 + 3]);
      *(float4*)&bufA[(8 + g) * 256 + r * 4] = ev;   // cols 32..63
    }
  }
  __syncthreads();

  // ---------------- Phase A (task-parallel): se L1 | V -----------------------
  if (wq < 8) {
    layerU<20, 8, true, true, false, false>(bufB, 0, bufB, 20, se_w1, 64,
                                            wq * 8, se_b1, r);
  } else {
    layerU<32, 4, false, true, true, false>(bufA, 32, bufB, 84, he_wv, 32,
                                            (wq - 8) * 4, he_bv, r);
  }
  __syncthreads();

  // ---------------- Phase B (task-parallel): se L2 | hand_ctx ----------------
  if (wq < 8) {
    layerU<64, 4, false, true, false, true>(bufB, 20, bufA, 64, se_w2, 32,
                                            wq * 4, se_b2, r);
  } else {
    const int j0 = (wq - 8) * 4;
    float acc[4];
#pragma unroll
    for (int j = 0; j < 4; ++j) acc[j] = he_bo[j0 + j];
#pragma unroll 4
    for (int k = 0; k < 32; ++k) {
      float a = bufB[(84 + k) * 64 + r];
      const float* wr = he_wo + (size_t)k * 32 + j0;
#pragma unroll
      for (int j = 0; j < 4; ++j) acc[j] += a * wr[j];
    }
    float scale = bufB[116 * 64 + r];
    float4 o = make_float4(scale * acc[0], scale * acc[1],
                           scale * acc[2], scale * acc[3]);
    *(float4*)&bufA[(j0 >> 2) * 256 + r * 4] = o;
  }
  __syncthreads();

  // ---------------- L1: 150->128 relu, PACKED (37 quads + tail) --------------
  {
    const int j0 = wq * 8;
    float2v A[4];
#pragma unroll
    for (int jp = 0; jp < 4; ++jp) A[jp] = *(const float2v*)&cx_b1[j0 + jp * 2];
#pragma unroll 8
    for (int g = 0; g < 37; ++g) {
      float4 a = *(const float4*)&bufA[g * 256 + r * 4];
#pragma unroll
      for (int q = 0; q < 4; ++q) {
        float av = (q == 0) ? a.x : (q == 1) ? a.y : (q == 2) ? a.z : a.w;
        float2v av2 = {av, av};
        const float* wr = cx_w1 + (size_t)(g * 4 + q) * 128 + j0;
#pragma unroll
        for (int jp = 0; jp < 4; ++jp) {
          float2v wv = *(const float2v*)&wr[jp * 2];
          A[jp] += av2 * wv;
        }
      }
    }
    {  // tail: cols 148,149 (discard elements 52,53)
      float4 a = *(const float4*)&bufA[37 * 256 + r * 4];
      float2v ax = {a.x, a.x}, ay = {a.y, a.y};
      const float* wr0 = cx_w1 + (size_t)148 * 128 + j0;
      const float* wr1 = cx_w1 + (size_t)149 * 128 + j0;
#pragma unroll
      for (int jp = 0; jp < 4; ++jp) {
        A[jp] += ax * (*(const float2v*)&wr0[jp * 2]);
        A[jp] += ay * (*(const float2v*)&wr1[jp * 2]);
      }
    }
#pragma unroll
    for (int qg = 0; qg < 2; ++qg) {
      float4 o = make_float4(fmaxf(A[qg * 2].x, 0.f), fmaxf(A[qg * 2].y, 0.f),
                             fmaxf(A[qg * 2 + 1].x, 0.f), fmaxf(A[qg * 2 + 1].y, 0.f));
      *(float4*)&bufB[((j0 >> 2) + qg) * 256 + r * 4] = o;   // h1 quad
    }
  }
  __syncthreads();

  // ---------------- L2: 128->128 relu, PACKED (bufB quad -> bufA quad) ------
  layer128P<true>(bufB, bufA, 0, cx_w2, 128, wq * 8, cx_b2, r);
  __syncthreads();

  // ---------------- P7 (L3 folded): t1 | P from h2, PACKED ------------------
  if (wq < 8) {
    layer128P<true>(bufA, bufB, 0, ws + 2048, 64, wq * 8, ws + 10240, r);
  } else {
    layer128P<false>(bufA, bufB, 64, ws + 10304, 64, (wq - 8) * 8, ws + 18496, r);
  }
  __syncthreads();

  // ---------------- P9: wave15 probs | waves 0-14 fused 2-action, PACKED ----
  float2v A0[16], A1[16];
  if (wq == 15) {
    float lg0 = atc_b2[0], lg1 = atc_b2[1], lg2 = atc_b2[2], lg3 = atc_b2[3];
#pragma unroll 4
    for (int g = 0; g < 16; ++g) {            // t1 = bufB quads 0..15
      float4 t = *(const float4*)&bufB[g * 256 + r * 4];
#pragma unroll
      for (int q = 0; q < 4; ++q) {
        float tv = (q == 0) ? t.x : (q == 1) ? t.y : (q == 2) ? t.z : t.w;
        const float* wr = atc_w2 + (size_t)(g * 4 + q) * 4;
        lg0 += tv * wr[0]; lg1 += tv * wr[1];
        lg2 += tv * wr[2]; lg3 += tv * wr[3];
      }
    }
    float m = fmaxf(fmaxf(lg0, lg1), fmaxf(lg2, lg3));
    float e0 = expf(lg0 - m), e1 = expf(lg1 - m), e2 = expf(lg2 - m), e3 = expf(lg3 - m);
    float inv = 1.f / (e0 + e1 + e2 + e3);
    bufA[r]       = (e0 - e1) * inv;   // tp0 - tp1
    bufA[64 + r]  = e1 * inv;          // tp1
    bufA[128 + r] = 2.f * e3 * inv;    // 2 * tp3
  } else {
    const int a0 = wq * 2;                     // wave-uniform
    const float* qa = ws + a0 * 64;            // uniform -> s_load
#pragma unroll
    for (int jp = 0; jp < 16; ++jp) { A0[jp] = 0.f; A1[jp] = 0.f; }
#pragma unroll 4
    for (int g = 0; g < 16; ++g) {             // P = bufB quads 16..31
      float4 pv = *(const float4*)&bufB[(16 + g) * 256 + r * 4];
#pragma unroll
      for (int q = 0; q < 4; ++q) {
        float p = (q == 0) ? pv.x : (q == 1) ? pv.y : (q == 2) ? pv.z : pv.w;
        const int k = g * 4 + q;
        float s0 = fmaxf(p + qa[k], 0.f);
        float s1 = fmaxf(p + qa[64 + k], 0.f);
        float2v s0v = {s0, s0}, s1v = {s1, s1};
        const float* w2r = as_w2 + (size_t)k * 32;   // uniform -> s_load
#pragma unroll
        for (int jp = 0; jp < 16; ++jp) {
          float2v wv = *(const float2v*)&w2r[jp * 2];
          A0[jp] += s0v * wv;                  // v_pk_fma_f32
          A1[jp] += s1v * wv;
        }
      }
    }
  }
  __syncthreads();   // waves 0-14 arrive late; only wave 15 really waits

  if (wq < 15) {
    const int a0 = wq * 2;
    const float b3v = as_b3[0];
    float sc0 = b3v, sc1 = b3v;
#pragma unroll
    for (int jp = 0; jp < 16; ++jp) {
      float b2a = as_b2[jp * 2], b2b = as_b2[jp * 2 + 1];
      float w3a = as_w3[jp * 2], w3b = as_w3[jp * 2 + 1];
      sc0 += fmaxf(A0[jp].x + b2a, 0.f) * w3a + fmaxf(A0[jp].y + b2b, 0.f) * w3b;
      sc1 += fmaxf(A1[jp].x + b2a, 0.f) * w3a + fmaxf(A1[jp].y + b2b, 0.f) * w3b;
    }
    float da = bufA[r], t1b = bufA[64 + r], t3x2 = bufA[128 + r];
    float st0 = ws[1920 + a0], hv0 = ws[1950 + a0];
    float st1 = ws[1921 + a0], hv1 = ws[1951 + a0];
    float bon0 = (hv0 > 0.5f) ? (t1b + st0 * da) : t3x2;
    float bon1 = (hv1 > 0.5f) ? (t1b + st1 * da) : t3x2;
    *(float2*)&out[(size_t)(b0 + r) * 30 + a0] =
        make_float2(sc0 + bon0, sc1 + bon1);
  }
}

// ---------------------------------------------------------------------------
extern "C" void kernel_launch(void* const* d_in, const int* in_sizes, int n_in,
                              void* d_out, int out_size, void* d_ws, size_t ws_size,
                              hipStream_t stream) {
  (void)in_sizes; (void)n_in; (void)out_size; (void)ws_size;
  const int* hand_cards = (const int*)d_in[0];
  const int* enemy_card = (const int*)d_in[1];
  const int* hand_size = (const int*)d_in[2];
  const float* game_state = (const float*)d_in[3];
  const float* discard = (const float*)d_in[4];
  const int* acards = (const int*)d_in[5];
  // d_in[6] = num_valid_actions (unused scalar)
  const float* val_emb = (const float*)d_in[7];
  const float* suit_emb = (const float*)d_in[8];
  const float* type_emb = (const float*)d_in[9];
  const float* ce_w1 = (const float*)d_in[10], * ce_b1 = (const float*)d_in[11];
  const float* ce_w2 = (const float*)d_in[12], * ce_b2 = (const float*)d_in[13];
  // d_in[14..21] = ha_* (hand self-attention) -- provably dead code, unused
  const float* he_wv = (const float*)d_in[26], * he_bv = (const float*)d_in[27];
  const float* he_wo = (const float*)d_in[28], * he_bo = (const float*)d_in[29];
  const float* se_w1 = (const float*)d_in[30], * se_b1 = (const float*)d_in[31];
  const float* se_w2 = (const float*)d_in[32], * se_b2 = (const float*)d_in[33];
  const float* atc_w1 = (const float*)d_in[34], * atc_b1 = (const float*)d_in[35];
  const float* atc_w2 = (const float*)d_in[36], * atc_b2 = (const float*)d_in[37];
  const float* as_w1 = (const float*)d_in[38], * as_b1 = (const float*)d_in[39];
  const float* as_w2 = (const float*)d_in[40], * as_b2 = (const float*)d_in[41];
  const float* as_w3 = (const float*)d_in[42], * as_b3 = (const float*)d_in[43];
  const float* cx_w1 = (const float*)d_in[44], * cx_b1 = (const float*)d_in[45];
  const float* cx_w2 = (const float*)d_in[46], * cx_b2 = (const float*)d_in[47];
  const float* cx_w3 = (const float*)d_in[48], * cx_b3 = (const float*)d_in[49];
  float* ws = (float*)d_ws;
  float* out = (float*)d_out;

  hipLaunchKernelGGL(precompute_kernel, dim3(33), dim3(256), 0, stream,
                     acards, val_emb, suit_emb, type_emb,
                     ce_w1, ce_b1, ce_w2, ce_b2, as_w1, as_b1,
                     cx_w3, cx_b3, atc_w1, atc_b1, ws);
  hipLaunchKernelGGL(policy_main, dim3(256), dim3(1024), 0, stream,
                     hand_cards, enemy_card, hand_size, game_state, discard,
                     val_emb, suit_emb, type_emb,
                     he_wv, he_bv, he_wo, he_bo,
                     se_w1, se_b1, se_w2, se_b2,
                     atc_w2, atc_b2,
                     as_w2, as_b2, as_w3, as_b3,
                     cx_w1, cx_b1, cx_w2, cx_b2,
                     ws, out);
}

// Round 9
// 221.268 us; speedup vs baseline: 1.1683x; 1.0521x over previous
//
#include <hip/hip_runtime.h>
#include <math.h>

// ---------------------------------------------------------------------------
// R24 = R16 (proven 75us: scalar s_load weight streams, P9 2-action fusion,
// wave15 logits dedup, L3 folded into P7) with the four big weight matrices
// PRE-TRANSPOSED into per-wave-contiguous slices in ws. Why: R23 proved the
// kernel is not issue-bound (packed FMA halved instrs, wall unchanged);
// R18 proved it's not occupancy-bound. The wall is the per-wave serial
// [s_load batch -> lgkmcnt(0) drain -> compute] chain; batches are
// SGPR-capacity-bound, so the lever is lines/loads per batch. Strided
// slices (32B useful per 512B row stride) touch a fresh 64B line per load;
// contiguous slices (T[wq][k][8], 4.8KB/wave) let the compiler merge into
// s_load_dwordx16 (2 rows/load, 1 line per 2 rows). Packed math reverted
// (R23: slight regression).
// ws layout (floats):
//   [0:1920) Qa | [1920:1950) strength | [1950:1980) hasv |
//   [10240:10304) b_t1 | [18496:18560) b_P |
//   [20480:28672) T_t1[8][128][8] | [28672:36864) T_P[8][128][8] |
//   [36864:56064) T_l1[16][150][8] | [56064:72448) T_l2[16][128][8]
// (ws_size >= 8.5MB established in R18; need 290KB.)
// ---------------------------------------------------------------------------

#define WS_TT1 20480
#define WS_TP  28672
#define WS_TL1 36864
#define WS_TL2 56064

__device__ __forceinline__ void encode_card32(int c,
                                              const float* __restrict__ val_emb,
                                              const float* __restrict__ suit_emb,
                                              const float* __restrict__ type_emb,
                                              float* e) {
  bool inv = (c == 0) || (c == 53);
  int v = inv ? 0 : ((c - 1) % 13 + 1);
  int s = inv ? 0 : ((c - 1) / 13 + 1);
  int ct = (v == 11) ? 1 : (v == 12) ? 2 : (v == 13) ? 3 : 0;
#pragma unroll
  for (int i = 0; i < 16; ++i) e[i] = val_emb[v * 16 + i];
#pragma unroll
  for (int i = 0; i < 16; ++i) e[16 + i] = suit_emb[s * 16 + i];
#pragma unroll
  for (int i = 0; i < 8; ++i) e[i] += type_emb[ct * 8 + i];
}

// ---------------------------------------------------------------------------
// Precompute, grid 68 x 256.
//  block 0:    action features + Qa + fused biases b_t1/b_P
//  blocks 1-32:  W_t1/W_P entries, written TRANSPOSED (T_t1/T_P)
//  blocks 33-51: cx_w1 -> T_l1 copy-transpose (19200 floats)
//  blocks 52-67: cx_w2 -> T_l2 copy-transpose (16384 floats)
// ---------------------------------------------------------------------------
__global__ __launch_bounds__(256) void precompute_kernel(
    const int* __restrict__ acards,
    const float* __restrict__ val_emb, const float* __restrict__ suit_emb,
    const float* __restrict__ type_emb,
    const float* __restrict__ ce_w1, const float* __restrict__ ce_b1,
    const float* __restrict__ ce_w2, const float* __restrict__ ce_b2,
    const float* __restrict__ as_w1, const float* __restrict__ as_b1,
    const float* __restrict__ cx_w3, const float* __restrict__ cx_b3,
    const float* __restrict__ atc_w1, const float* __restrict__ atc_b1,
    const float* __restrict__ cx_w1, const float* __restrict__ cx_w2,
    float* __restrict__ ws) {
  const int tid = threadIdx.x;
  const int bid = blockIdx.x;

  if (bid >= 52) {                       // cx_w2 -> T_l2 (k<128, j<128)
    const int base = (bid - 52) * 1024 + tid * 4;
#pragma unroll
    for (int i = 0; i < 4; ++i) {
      int e = base + i;                  // < 16384 always (16 blocks x 1024)
      int k = e >> 7, j = e & 127;
      ws[WS_TL2 + (j >> 3) * 1024 + k * 8 + (j & 7)] = cx_w2[e];
    }
    return;
  }
  if (bid >= 33) {                       // cx_w1 -> T_l1 (k<150, j<128)
    const int base = (bid - 33) * 1024 + tid * 4;
#pragma unroll
    for (int i = 0; i < 4; ++i) {
      int e = base + i;
      if (e < 19200) {
        int k = e >> 7, j = e & 127;
        ws[WS_TL1 + (j >> 3) * 1200 + k * 8 + (j & 7)] = cx_w1[e];
      }
    }
    return;
  }
  if (bid > 0) {                         // fused W_t1/W_P, transposed write
    const int idx = (bid - 1) * 256 + tid;
    const int k = idx >> 6, j = idx & 63;
    float at = 0.f, ap = 0.f;
#pragma unroll 8
    for (int m = 0; m < 128; ++m) {
      float c = cx_w3[k * 128 + m];
      at += c * atc_w1[m * 64 + j];
      ap += c * as_w1[(size_t)m * 64 + j];
    }
    const int dst = (j >> 3) * 1024 + k * 8 + (j & 7);
    ws[WS_TT1 + dst] = at;
    ws[WS_TP + dst] = ap;
    return;
  }

  // ----- block 0: biases + action features + Qa -----
  __shared__ float sAct[30][32];
  __shared__ float sCombo[30][16];

  if (tid >= 64 && tid < 128) {
    const int j = tid - 64;
    float bt = atc_b1[j], bp = 0.f;
#pragma unroll 8
    for (int m = 0; m < 128; ++m) {
      float c = cx_b3[m];
      bt += c * atc_w1[m * 64 + j];
      bp += c * as_w1[(size_t)m * 64 + j];
    }
    ws[10240 + j] = bt;
    ws[18496 + j] = bp;
  }

  if (tid < 30) {
    int c[4];
#pragma unroll
    for (int i = 0; i < 4; ++i) c[i] = acards[tid * 4 + i];
    bool mask[4]; int vals[4], suits[4]; int csize = 0; bool hasv = false;
#pragma unroll
    for (int i = 0; i < 4; ++i) {
      mask[i] = (c[i] != 0);
      if (mask[i]) { csize++; hasv = true; }
      vals[i] = mask[i] ? ((c[i] - 1) % 13 + 1) : 0;
      suits[i] = mask[i] ? ((c[i] - 1) / 13 + 1) : 0;
    }
    int fvv = mask[0] ? vals[0] : mask[1] ? vals[1] : mask[2] ? vals[2]
              : mask[3] ? vals[3] : vals[0];
    bool same = true;
#pragma unroll
    for (int i = 0; i < 4; ++i) if (mask[i] && vals[i] != fvv) same = false;
    float total = 0.f;
#pragma unroll
    for (int i = 0; i < 4; ++i) {
      if (mask[i]) {
        int v = vals[i];
        total += (v == 1) ? 1.f : (v == 11) ? 10.f : (v == 12) ? 15.f
                 : (v == 13) ? 20.f : (float)v;
      }
    }
    float uniq = 0.f;
#pragma unroll
    for (int s = 1; s <= 4; ++s) {
      bool any = false;
#pragma unroll
      for (int i = 0; i < 4; ++i) if (suits[i] == s) any = true;
      uniq += any ? 1.f : 0.f;
    }
    bool ace = false;
#pragma unroll
    for (int i = 0; i < 4; ++i) if (mask[i] && vals[i] == 1) ace = true;
    float f_same = same ? 1.f : 0.f, f_ace = ace ? 1.f : 0.f;
    float valid = (((float)csize <= 4.f) && (f_same > 0.f || f_ace > 0.f)) ? 1.f : 0.f;
    float feats[6] = {(float)csize, f_same, total, uniq, f_ace, valid};
    if (!hasv) { for (int i = 0; i < 6; ++i) feats[i] = 0.f; }
    float emb[32];
#pragma unroll
    for (int i = 0; i < 32; ++i) emb[i] = 0.f;
    float cnt = 0.f;
#pragma unroll
    for (int i = 0; i < 4; ++i) {
      float e[32];
      encode_card32(c[i], val_emb, suit_emb, type_emb, e);
      if (mask[i]) {
#pragma unroll
        for (int j = 0; j < 32; ++j) emb[j] += e[j];
        cnt += 1.f;
      }
    }
    float invc = 1.f / fmaxf(cnt, 1.f);
#pragma unroll
    for (int j = 0; j < 32; ++j) sAct[tid][j] = hasv ? emb[j] * invc : 0.f;
    float t32[32];
#pragma unroll
    for (int j = 0; j < 32; ++j) {
      float acc = ce_b1[j];
#pragma unroll
      for (int k = 0; k < 6; ++k) acc += feats[k] * ce_w1[k * 32 + j];
      t32[j] = fmaxf(acc, 0.f);
    }
#pragma unroll
    for (int j = 0; j < 16; ++j) {
      float acc = ce_b2[j];
#pragma unroll
      for (int k = 0; k < 32; ++k) acc += t32[k] * ce_w2[k * 16 + j];
      sCombo[tid][j] = acc;
    }
    ws[1920 + tid] = total * 0.05f;
    ws[1950 + tid] = hasv ? 1.f : 0.f;
  }
  __syncthreads();
  for (int idx = tid; idx < 1920; idx += 256) {
    int a = idx >> 6, j = idx & 63;
    float acc = as_b1[j];
#pragma unroll
    for (int k = 0; k < 32; ++k) acc += sAct[a][k] * as_w1[(128 + k) * 64 + j];
#pragma unroll
    for (int k = 0; k < 16; ++k) acc += sCombo[a][k] * as_w1[(160 + k) * 64 + j];
    ws[idx] = acc;
  }
}

// ---------------------------------------------------------------------------
// layerU (scalar, R16 verbatim) for the SMALL phases A/B only.
// ---------------------------------------------------------------------------
template <int K, int NJ, bool RELU, bool HASB, bool QIN, bool QOUT>
__device__ __forceinline__ void layerU(
    const float* __restrict__ in, int inColBase, float* __restrict__ outB,
    int outColBase, const float* __restrict__ W, int ldw, int j0,
    const float* __restrict__ bias, int r) {
  float acc[NJ];
#pragma unroll
  for (int j = 0; j < NJ; ++j) acc[j] = HASB ? bias[j0 + j] : 0.f;
  if constexpr (QIN) {
    static_assert(K % 4 == 0, "quad input needs K%4==0");
    const int g0 = inColBase >> 2;
#pragma unroll 8
    for (int g = 0; g < K / 4; ++g) {
      float4 a = *(const float4*)&in[(g0 + g) * 256 + r * 4];
#pragma unroll
      for (int q = 0; q < 4; ++q) {
        float av = (q == 0) ? a.x : (q == 1) ? a.y : (q == 2) ? a.z : a.w;
        const float* wr = W + (size_t)(g * 4 + q) * ldw + j0;
#pragma unroll
        for (int j = 0; j < NJ; ++j) acc[j] += av * wr[j];
      }
    }
  } else {
#pragma unroll 4
    for (int k = 0; k < K; ++k) {
      float a = in[(inColBase + k) * 64 + r];
      const float* wr = W + (size_t)k * ldw + j0;
#pragma unroll
      for (int j = 0; j < NJ; ++j) acc[j] += a * wr[j];
    }
  }
#pragma unroll
  for (int j = 0; j < NJ; ++j) if (RELU) acc[j] = fmaxf(acc[j], 0.f);
  if constexpr (QOUT && (NJ % 4 == 0)) {
    const int c0 = outColBase + j0;
#pragma unroll
    for (int qg = 0; qg < NJ / 4; ++qg) {
      float4 o = make_float4(acc[qg * 4], acc[qg * 4 + 1],
                             acc[qg * 4 + 2], acc[qg * 4 + 3]);
      *(float4*)&outB[((c0 >> 2) + qg) * 256 + r * 4] = o;
    }
  } else {
#pragma unroll
    for (int j = 0; j < NJ; ++j) outB[(outColBase + j0 + j) * 64 + r] = acc[j];
  }
}

// ---------------------------------------------------------------------------
// layerT: K->8 layer reading a per-wave-CONTIGUOUS weight slice T[k][8]
// (s_load merges to dwordx16: 2 k-rows per load, 1 cache line per 2 rows).
// Quad in -> quad out. Used by L2 (K=128) and P7.
// ---------------------------------------------------------------------------
template <int K, bool RELU>
__device__ __forceinline__ void layerT(
    const float* __restrict__ in, float* __restrict__ outB, int outColBase,
    const float* __restrict__ T, int j0,
    const float* __restrict__ bias, int r) {
  float acc[8];
#pragma unroll
  for (int j = 0; j < 8; ++j) acc[j] = bias[j0 + j];
#pragma unroll 8
  for (int g = 0; g < K / 4; ++g) {
    float4 a = *(const float4*)&in[g * 256 + r * 4];
#pragma unroll
    for (int q = 0; q < 4; ++q) {
      float av = (q == 0) ? a.x : (q == 1) ? a.y : (q == 2) ? a.z : a.w;
      const float* wr = T + (g * 4 + q) * 8;
#pragma unroll
      for (int j = 0; j < 8; ++j) acc[j] += av * wr[j];
    }
  }
#pragma unroll
  for (int j = 0; j < 8; ++j) if (RELU) acc[j] = fmaxf(acc[j], 0.f);
  const int c0 = outColBase + j0;
#pragma unroll
  for (int qg = 0; qg < 2; ++qg) {
    float4 o = make_float4(acc[qg * 4], acc[qg * 4 + 1],
                           acc[qg * 4 + 2], acc[qg * 4 + 3]);
    *(float4*)&outB[((c0 >> 2) + qg) * 256 + r * 4] = o;
  }
}

// ---------------------------------------------------------------------------
// Main kernel. 64 rows/block, 1024 threads (16 waves), grid 256. R16 layout:
// bufA (quad, 152 cols): [0:32) hand_ctx | [32:64) enemy | [64:96) strat_ctx |
//   [96:150) discard -> later h2 (128) -> later per-row prob coefs [0:192)
// bufB: rows [0:20) strat_in | [20:84) t64 | [84:116) V | 116 sLen
//   -> quad h1 -> P7 out: t1 quads 0..15 | P quads 16..31
// ---------------------------------------------------------------------------
__global__ __launch_bounds__(1024) void policy_main(
    const int* __restrict__ hand_cards, const int* __restrict__ enemy_card,
    const int* __restrict__ hand_size, const float* __restrict__ game_state,
    const float* __restrict__ discard,
    const float* __restrict__ val_emb, const float* __restrict__ suit_emb,
    const float* __restrict__ type_emb,
    const float* __restrict__ he_wv, const float* __restrict__ he_bv,
    const float* __restrict__ he_wo, const float* __restrict__ he_bo,
    const float* __restrict__ se_w1, const float* __restrict__ se_b1,
    const float* __restrict__ se_w2, const float* __restrict__ se_b2,
    const float* __restrict__ atc_w2, const float* __restrict__ atc_b2,
    const float* __restrict__ as_w2, const float* __restrict__ as_b2,
    const float* __restrict__ as_w3, const float* __restrict__ as_b3,
    const float* __restrict__ cx_b1, const float* __restrict__ cx_b2,
    const float* __restrict__ ws, float* __restrict__ out) {
  __shared__ float bufA[38 * 256];   // 38 KB
  __shared__ float bufB[128 * 64];   // 32 KB

  const int tid = threadIdx.x;
  const int r = tid & 63;                                   // lane = batch row
  const int wq = __builtin_amdgcn_readfirstlane(tid >> 6);  // wave id 0..15
  const int b0 = blockIdx.x * 64;

  // ---------------- P0: staging + per-row features --------------------------
  for (int idx = tid; idx < 64 * 54; idx += 1024) {          // discard -> bufA
    int rr = idx / 54, k = idx - rr * 54;
    int c = 96 + k;
    bufA[(c >> 2) * 256 + rr * 4 + (c & 3)] = discard[(size_t)b0 * 54 + idx];
  }
  if (wq == 2) {                                            // game_state rows 0..9
#pragma unroll
    for (int k = 0; k < 10; ++k)
      bufB[k * 64 + r] = game_state[(size_t)(b0 + r) * 10 + k];
  }
  if (wq == 0) {                                            // hand features rows 10..19
    const int b = b0 + r;
    const float hsz = (float)hand_size[b];
    int aces = 0, faces = 0, low = 0, c1 = 0, c2 = 0, c3 = 0, c4 = 0;
#pragma unroll
    for (int i = 0; i < 8; ++i) {
      int c = hand_cards[b * 8 + i];
      int v = (c == 0) ? 0 : ((c - 1) % 13 + 1);
      int s = (c == 0) ? 0 : ((c - 1) / 13 + 1);
      aces += (v == 1);
      faces += (v >= 11 && v <= 13);
      low += (v >= 2 && v <= 6);
      c1 += (s == 1); c2 += (s == 2); c3 += (s == 3); c4 += (s == 4);
    }
    float sdiv = (float)((c1 > 0) + (c2 > 0) + (c3 > 0) + (c4 > 0)) * 0.25f;
    float hvr = (float)faces / (hsz + 1e-8f);
    bufB[(10 + 0) * 64 + r] = hsz;          bufB[(10 + 1) * 64 + r] = (float)aces;
    bufB[(10 + 2) * 64 + r] = (float)faces; bufB[(10 + 3) * 64 + r] = (float)low;
    bufB[(10 + 4) * 64 + r] = (float)c1;    bufB[(10 + 5) * 64 + r] = (float)c2;
    bufB[(10 + 6) * 64 + r] = (float)c3;    bufB[(10 + 7) * 64 + r] = (float)c4;
    bufB[(10 + 8) * 64 + r] = hvr;          bufB[(10 + 9) * 64 + r] = sdiv;
  }
  if (wq == 1) {                                            // enemy (quad) + sLen
    const int b = b0 + r;
    bufB[116 * 64 + r] = 8.0f / fmaxf((float)hand_size[b], 1.0f);
    float e[32];
    encode_card32(enemy_card[b], val_emb, suit_emb, type_emb, e);
#pragma unroll
    for (int g = 0; g < 8; ++g) {
      float4 ev = make_float4(e[g * 4], e[g * 4 + 1], e[g * 4 + 2], e[g * 4 + 3]);
      *(float4*)&bufA[(8 + g) * 256 + r * 4] = ev;   // cols 32..63
    }
  }
  __syncthreads();

  // ---------------- Phase A (task-parallel): se L1 | V -----------------------
  if (wq < 8) {
    layerU<20, 8, true, true, false, false>(bufB, 0, bufB, 20, se_w1, 64,
                                            wq * 8, se_b1, r);
  } else {
    layerU<32, 4, false, true, true, false>(bufA, 32, bufB, 84, he_wv, 32,
                                            (wq - 8) * 4, he_bv, r);
  }
  __syncthreads();

  // ---------------- Phase B (task-parallel): se L2 | hand_ctx ----------------
  if (wq < 8) {
    layerU<64, 4, false, true, false, true>(bufB, 20, bufA, 64, se_w2, 32,
                                            wq * 4, se_b2, r);
  } else {
    const int j0 = (wq - 8) * 4;
    float acc[4];
#pragma unroll
    for (int j = 0; j < 4; ++j) acc[j] = he_bo[j0 + j];
#pragma unroll 4
    for (int k = 0; k < 32; ++k) {
      float a = bufB[(84 + k) * 64 + r];
      const float* wr = he_wo + (size_t)k * 32 + j0;
#pragma unroll
      for (int j = 0; j < 4; ++j) acc[j] += a * wr[j];
    }
    float scale = bufB[116 * 64 + r];
    float4 o = make_float4(scale * acc[0], scale * acc[1],
                           scale * acc[2], scale * acc[3]);
    *(float4*)&bufA[(j0 >> 2) * 256 + r * 4] = o;
  }
  __syncthreads();

  // ---------------- L1: 150->128 relu, contiguous T_l1 slice ----------------
  {
    const int j0 = wq * 8;
    const float* T = ws + WS_TL1 + wq * 1200;   // [150][8] contiguous
    float acc[8];
#pragma unroll
    for (int j = 0; j < 8; ++j) acc[j] = cx_b1[j0 + j];
#pragma unroll 8
    for (int g = 0; g < 37; ++g) {
      float4 a = *(const float4*)&bufA[g * 256 + r * 4];
#pragma unroll
      for (int q = 0; q < 4; ++q) {
        float av = (q == 0) ? a.x : (q == 1) ? a.y : (q == 2) ? a.z : a.w;
        const float* wr = T + (g * 4 + q) * 8;
#pragma unroll
        for (int j = 0; j < 8; ++j) acc[j] += av * wr[j];
      }
    }
    {  // tail: cols 148,149 (discard elements 52,53)
      float4 a = *(const float4*)&bufA[37 * 256 + r * 4];
      const float* wr0 = T + 148 * 8;
      const float* wr1 = T + 149 * 8;
#pragma unroll
      for (int j = 0; j < 8; ++j) acc[j] += a.x * wr0[j] + a.y * wr1[j];
    }
#pragma unroll
    for (int qg = 0; qg < 2; ++qg) {
      float4 o = make_float4(fmaxf(acc[qg * 4], 0.f), fmaxf(acc[qg * 4 + 1], 0.f),
                             fmaxf(acc[qg * 4 + 2], 0.f), fmaxf(acc[qg * 4 + 3], 0.f));
      *(float4*)&bufB[((j0 >> 2) + qg) * 256 + r * 4] = o;   // h1 quad
    }
  }
  __syncthreads();

  // ---------------- L2: 128->128 relu, contiguous T_l2 slice ----------------
  layerT<128, true>(bufB, bufA, 0, ws + WS_TL2 + wq * 1024, wq * 8, cx_b2, r);
  __syncthreads();

  // ---------------- P7 (L3 folded): t1 | P from h2, contiguous slices -------
  if (wq < 8) {
    layerT<128, true>(bufA, bufB, 0, ws + WS_TT1 + wq * 1024, wq * 8,
                      ws + 10240, r);
  } else {
    layerT<128, false>(bufA, bufB, 64, ws + WS_TP + (wq - 8) * 1024,
                       (wq - 8) * 8, ws + 18496, r);
  }
  __syncthreads();

  // ---------------- P9: wave15 probs | waves 0-14 fused 2-action MLP --------
  float acc0[32], acc1[32];
  if (wq == 15) {
    float lg0 = atc_b2[0], lg1 = atc_b2[1], lg2 = atc_b2[2], lg3 = atc_b2[3];
#pragma unroll 4
    for (int g = 0; g < 16; ++g) {            // t1 = bufB quad groups 0..15
      float4 t = *(const float4*)&bufB[g * 256 + r * 4];
#pragma unroll
      for (int q = 0; q < 4; ++q) {
        float tv = (q == 0) ? t.x : (q == 1) ? t.y : (q == 2) ? t.z : t.w;
        const float* wr = atc_w2 + (size_t)(g * 4 + q) * 4;
        lg0 += tv * wr[0]; lg1 += tv * wr[1];
        lg2 += tv * wr[2]; lg3 += tv * wr[3];
      }
    }
    float m = fmaxf(fmaxf(lg0, lg1), fmaxf(lg2, lg3));
    float e0 = expf(lg0 - m), e1 = expf(lg1 - m), e2 = expf(lg2 - m), e3 = expf(lg3 - m);
    float inv = 1.f / (e0 + e1 + e2 + e3);
    bufA[r]       = (e0 - e1) * inv;   // tp0 - tp1
    bufA[64 + r]  = e1 * inv;          // tp1
    bufA[128 + r] = 2.f * e3 * inv;    // 2 * tp3
  } else {
    const int a0 = wq * 2;                     // wave-uniform
    const float* qa = ws + a0 * 64;            // uniform -> s_load
#pragma unroll
    for (int j = 0; j < 32; ++j) { acc0[j] = 0.f; acc1[j] = 0.f; }
#pragma unroll 4
    for (int g = 0; g < 16; ++g) {             // P = bufB quad groups 16..31
      float4 pv = *(const float4*)&bufB[(16 + g) * 256 + r * 4];
#pragma unroll
      for (int q = 0; q < 4; ++q) {
        float p = (q == 0) ? pv.x : (q == 1) ? pv.y : (q == 2) ? pv.z : pv.w;
        const int k = g * 4 + q;
        float s0 = fmaxf(p + qa[k], 0.f);
        float s1 = fmaxf(p + qa[64 + k], 0.f);
        const float* w2r = as_w2 + (size_t)k * 32;
#pragma unroll
        for (int j = 0; j < 32; ++j) {
          float w = w2r[j];
          acc0[j] += s0 * w;
          acc1[j] += s1 * w;
        }
      }
    }
  }
  __syncthreads();   // waves 0-14 arrive late; only wave 15 actually waits

  if (wq < 15) {
    const int a0 = wq * 2;
    const float b3v = as_b3[0];
    float sc0 = b3v, sc1 = b3v;
#pragma unroll
    for (int j = 0; j < 32; ++j) {
      float b2 = as_b2[j], w3 = as_w3[j];
      sc0 += fmaxf(acc0[j] + b2, 0.f) * w3;
      sc1 += fmaxf(acc1[j] + b2, 0.f) * w3;
    }
    float da = bufA[r], t1b = bufA[64 + r], t3x2 = bufA[128 + r];
    float st0 = ws[1920 + a0], hv0 = ws[1950 + a0];
    float st1 = ws[1921 + a0], hv1 = ws[1951 + a0];
    float bon0 = (hv0 > 0.5f) ? (t1b + st0 * da) : t3x2;
    float bon1 = (hv1 > 0.5f) ? (t1b + st1 * da) : t3x2;
    *(float2*)&out[(size_t)(b0 + r) * 30 + a0] =
        make_float2(sc0 + bon0, sc1 + bon1);
  }
}

// ---------------------------------------------------------------------------
extern "C" void kernel_launch(void* const* d_in, const int* in_sizes, int n_in,
                              void* d_out, int out_size, void* d_ws, size_t ws_size,
                              hipStream_t stream) {
  (void)in_sizes; (void)n_in; (void)out_size; (void)ws_size;
  const int* hand_cards = (const int*)d_in[0];
  const int* enemy_card = (const int*)d_in[1];
  const int* hand_size = (const int*)d_in[2];
  const float* game_state = (const float*)d_in[3];
  const float* discard = (const float*)d_in[4];
  const int* acards = (const int*)d_in[5];
  // d_in[6] = num_valid_actions (unused scalar)
  const float* val_emb = (const float*)d_in[7];
  const float* suit_emb = (const float*)d_in[8];
  const float* type_emb = (const float*)d_in[9];
  const float* ce_w1 = (const float*)d_in[10], * ce_b1 = (const float*)d_in[11];
  const float* ce_w2 = (const float*)d_in[12], * ce_b2 = (const float*)d_in[13];
  // d_in[14..21] = ha_* (hand self-attention) -- provably dead code, unused
  const float* he_wv = (const float*)d_in[26], * he_bv = (const float*)d_in[27];
  const float* he_wo = (const float*)d_in[28], * he_bo = (const float*)d_in[29];
  const float* se_w1 = (const float*)d_in[30], * se_b1 = (const float*)d_in[31];
  const float* se_w2 = (const float*)d_in[32], * se_b2 = (const float*)d_in[33];
  const float* atc_w1 = (const float*)d_in[34], * atc_b1 = (const float*)d_in[35];
  const float* atc_w2 = (const float*)d_in[36], * atc_b2 = (const float*)d_in[37];
  const float* as_w1 = (const float*)d_in[38], * as_b1 = (const float*)d_in[39];
  const float* as_w2 = (const float*)d_in[40], * as_b2 = (const float*)d_in[41];
  const float* as_w3 = (const float*)d_in[42], * as_b3 = (const float*)d_in[43];
  const float* cx_w1 = (const float*)d_in[44], * cx_b1 = (const float*)d_in[45];
  const float* cx_w2 = (const float*)d_in[46], * cx_b2 = (const float*)d_in[47];
  const float* cx_w3 = (const float*)d_in[48], * cx_b3 = (const float*)d_in[49];
  float* ws = (float*)d_ws;
  float* out = (float*)d_out;

  hipLaunchKernelGGL(precompute_kernel, dim3(68), dim3(256), 0, stream,
                     acards, val_emb, suit_emb, type_emb,
                     ce_w1, ce_b1, ce_w2, ce_b2, as_w1, as_b1,
                     cx_w3, cx_b3, atc_w1, atc_b1, cx_w1, cx_w2, ws);
  hipLaunchKernelGGL(policy_main, dim3(256), dim3(1024), 0, stream,
                     hand_cards, enemy_card, hand_size, game_state, discard,
                     val_emb, suit_emb, type_emb,
                     he_wv, he_bv, he_wo, he_bo,
                     se_w1, se_b1, se_w2, se_b2,
                     atc_w2, atc_b2,
                     as_w2, as_b2, as_w3, as_b3,
                     cx_b1, cx_b2,
                     ws, out);
}